// Round 3
// baseline (327.099 us; speedup 1.0000x reference)
//
#include <hip/hip_runtime.h>
#include <hip/hip_bf16.h>
#include <cmath>

#define D 256
#define NH 8
#define B 2
#define EPW 4      // edges per wave (round-0 value; EPW=8 regressed in R2)
#define NBMAX 512  // buckets for counting sort (bucket = node >> 6)

__device__ inline unsigned short f2bf(float f) {
    unsigned u = __float_as_uint(f);
    unsigned r = u + 0x7FFFu + ((u >> 16) & 1u);   // RNE
    return (unsigned short)(r >> 16);
}

// K0: fp32 [bb][node][d] -> packed bf16 [node][bb][d] (1KB per node covers
// both batches). One thread = 8 floats -> one 16B uint4 store.
__global__ __launch_bounds__(256) void k_conv(
    const float* __restrict__ q, const float* __restrict__ k,
    uint4* __restrict__ qc, uint4* __restrict__ kc, int n)
{
    int total = n * B * 32;
    for (int i = blockIdx.x * blockDim.x + threadIdx.x; i < total;
         i += gridDim.x * blockDim.x) {
        int c   = i & 31;
        int row = i >> 5;                 // bb*n + node
        int bb  = (row >= n) ? 1 : 0;
        int node = row - bb * n;
        const float4* qs = (const float4*)(q + ((size_t)row << 8)) + (c << 1);
        const float4* ks = (const float4*)(k + ((size_t)row << 8)) + (c << 1);
        float4 a0 = qs[0], a1 = qs[1];
        float4 b0 = ks[0], b1 = ks[1];
        uint4 pa, pb;
        pa.x = (unsigned)f2bf(a0.x) | ((unsigned)f2bf(a0.y) << 16);
        pa.y = (unsigned)f2bf(a0.z) | ((unsigned)f2bf(a0.w) << 16);
        pa.z = (unsigned)f2bf(a1.x) | ((unsigned)f2bf(a1.y) << 16);
        pa.w = (unsigned)f2bf(a1.z) | ((unsigned)f2bf(a1.w) << 16);
        pb.x = (unsigned)f2bf(b0.x) | ((unsigned)f2bf(b0.y) << 16);
        pb.y = (unsigned)f2bf(b0.z) | ((unsigned)f2bf(b0.w) << 16);
        pb.z = (unsigned)f2bf(b1.x) | ((unsigned)f2bf(b1.y) << 16);
        pb.w = (unsigned)f2bf(b1.z) | ((unsigned)f2bf(b1.w) << 16);
        size_t dst = ((size_t)node * B + bb) * 32 + c;
        qc[dst] = pa;
        kc[dst] = pb;
    }
}

// S1: per-block LDS histogram of e0 buckets (bucket = e0 >> 6).
__global__ __launch_bounds__(256) void k_hist(
    const int* __restrict__ e, int* __restrict__ hist, int m)
{
    __shared__ int lh[NBMAX];
    for (int t = threadIdx.x; t < NBMAX; t += 256) lh[t] = 0;
    __syncthreads();
    for (int j = blockIdx.x * blockDim.x + threadIdx.x; j < m;
         j += gridDim.x * blockDim.x)
        atomicAdd(&lh[e[j] >> 6], 1);
    __syncthreads();
    for (int t = threadIdx.x; t < NBMAX; t += 256)
        if (lh[t]) atomicAdd(&hist[t], lh[t]);
}

// S2: single-block exclusive scan of NBMAX counters -> cursor.
__global__ __launch_bounds__(NBMAX) void k_scan(
    const int* __restrict__ hist, int* __restrict__ cursor)
{
    __shared__ int tmp[NBMAX];
    int t = threadIdx.x;
    int own = hist[t];
    tmp[t] = own;
    __syncthreads();
    for (int off = 1; off < NBMAX; off <<= 1) {
        int v = (t >= off) ? tmp[t - off] : 0;
        __syncthreads();
        tmp[t] += v;
        __syncthreads();
    }
    cursor[t] = tmp[t] - own;   // exclusive prefix
}

// S3: scatter edges into bucket-sorted order. perm[pos] = {e0, e1, r, orig_j}.
__global__ __launch_bounds__(256) void k_scatter(
    const int* __restrict__ e, const int* __restrict__ r,
    int* __restrict__ cursor, int4* __restrict__ perm, int m)
{
    for (int j = blockIdx.x * blockDim.x + threadIdx.x; j < m;
         j += gridDim.x * blockDim.x) {
        int e0 = e[j];
        int pos = atomicAdd(&cursor[e0 >> 6], 1);
        perm[pos] = make_int4(e0, e[m + j], r[j], j);
    }
}

// K1: gather + scores + exp + segment atomicAdd over BUCKET-SORTED edges.
// Theory (R3): the 91us kernel was bound by the L2-miss path: 655MB logical
// gather vs 41MB table (16x redundancy), random order -> no L2 temporal
// locality (4MB/XCD vs 41MB table), 294MB re-streamed from L3/HBM per
// dispatch at ~3.8 TB/s. Sorting edges by e0-bucket (64 nodes = 64KB of
// q-rows) + XCD-chunked block swizzle gives each XCD a distinct ~2.6MB
// q-window -> L2-resident -> q-side L2-miss traffic drops ~147MB -> ~20MB.
__global__ __launch_bounds__(256) void k_scores_perm(
    const ushort* __restrict__ qc, const ushort* __restrict__ kc,
    const int4* __restrict__ perm,
    float* __restrict__ s, float* __restrict__ seg, int m, int do_swz)
{
    int bid = blockIdx.x;
    if (do_swz) {                       // XCD-chunked (bijective: grid%8==0)
        int nb8 = gridDim.x >> 3;
        bid = (bid & 7) * nb8 + (bid >> 3);
    }
    int wave = (bid << 2) + (threadIdx.x >> 6);
    int lane = threadIdx.x & 63;
    int j0 = wave * EPW;
    if (j0 >= m) return;

    int rr[EPW], jo[EPW];
    uint4 qa[EPW], kb[EPW];
    #pragma unroll
    for (int t = 0; t < EPW; ++t) {
        int j = j0 + t;
        int4 p = (j < m) ? perm[j] : make_int4(0, 0, 0, -1);
        rr[t] = p.z;
        jo[t] = p.w;   // original edge index (or -1 = inactive)
        qa[t] = ((const uint4*)(qc + (size_t)p.x * (B * D)))[lane];
        kb[t] = ((const uint4*)(kc + (size_t)p.y * (B * D)))[lane];
    }

    #pragma unroll
    for (int t = 0; t < EPW; ++t) {
        float p = 0.f;
        const unsigned* qw = (const unsigned*)&qa[t];
        const unsigned* kw = (const unsigned*)&kb[t];
        #pragma unroll
        for (int w = 0; w < 4; ++w) {
            float ql = __uint_as_float(qw[w] << 16);
            float qh = __uint_as_float(qw[w] & 0xFFFF0000u);
            float kl = __uint_as_float(kw[w] << 16);
            float kh = __uint_as_float(kw[w] & 0xFFFF0000u);
            p = fmaf(ql, kl, p);
            p = fmaf(qh, kh, p);
        }
        p += __shfl_xor(p, 1);
        p += __shfl_xor(p, 2);
        float ex = __expf(p * 0.0625f);     // /sqrt(256), no max shift
        if ((lane & 3) == 0 && jo[t] >= 0) {
            int bb = lane >> 5;
            int h  = (lane >> 2) & 7;
            s[((size_t)bb * m + jo[t]) * NH + h] = ex;
            atomicAdd(&seg[((size_t)rr[t] * B + bb) * NH + h], ex);
        }
    }
}

// K1-direct: original-order fallback (round-0 structure, used when ws too
// small for the perm buffer).
__global__ __launch_bounds__(256) void k_scores_fused(
    const ushort* __restrict__ qc, const ushort* __restrict__ kc,
    const int* __restrict__ e, const int* __restrict__ r,
    float* __restrict__ s, float* __restrict__ seg, int m)
{
    int wave = (int)((blockIdx.x * blockDim.x + threadIdx.x) >> 6);
    int lane = threadIdx.x & 63;
    int j0 = wave * EPW;
    if (j0 >= m) return;

    int e0[EPW], e1[EPW], rr[EPW];
    #pragma unroll
    for (int t = 0; t < EPW; ++t) {
        int j = j0 + t;
        int ok = (j < m);
        e0[t] = ok ? e[j]     : 0;
        e1[t] = ok ? e[m + j] : 0;
        rr[t] = ok ? r[j]     : 0;
    }
    uint4 qa[EPW], kb[EPW];
    #pragma unroll
    for (int t = 0; t < EPW; ++t) {
        qa[t] = ((const uint4*)(qc + (size_t)e0[t] * (B * D)))[lane];
        kb[t] = ((const uint4*)(kc + (size_t)e1[t] * (B * D)))[lane];
    }
    #pragma unroll
    for (int t = 0; t < EPW; ++t) {
        float p = 0.f;
        const unsigned* qw = (const unsigned*)&qa[t];
        const unsigned* kw = (const unsigned*)&kb[t];
        #pragma unroll
        for (int w = 0; w < 4; ++w) {
            float ql = __uint_as_float(qw[w] << 16);
            float qh = __uint_as_float(qw[w] & 0xFFFF0000u);
            float kl = __uint_as_float(kw[w] << 16);
            float kh = __uint_as_float(kw[w] & 0xFFFF0000u);
            p = fmaf(ql, kl, p);
            p = fmaf(qh, kh, p);
        }
        p += __shfl_xor(p, 1);
        p += __shfl_xor(p, 2);
        float ex = __expf(p * 0.0625f);
        if ((lane & 3) == 0 && (j0 + t) < m) {
            int bb = lane >> 5;
            int h  = (lane >> 2) & 7;
            s[((size_t)bb * m + (j0 + t)) * NH + h] = ex;
            atomicAdd(&seg[((size_t)rr[t] * B + bb) * NH + h], ex);
        }
    }
}

// fp32 fallback (ws too small for bf16 buffers): same fused structure.
__global__ __launch_bounds__(256) void k_scores_fused_f32(
    const float* __restrict__ q, const float* __restrict__ k,
    const int* __restrict__ e, const int* __restrict__ r,
    float* __restrict__ s, float* __restrict__ seg, int n, int m)
{
    int wave = (int)((blockIdx.x * blockDim.x + threadIdx.x) >> 6);
    int lane = threadIdx.x & 63;
    int j0 = wave * EPW;
    if (j0 >= m) return;
    int e0[EPW], e1[EPW], rr[EPW];
    #pragma unroll
    for (int t = 0; t < EPW; ++t) {
        int j = j0 + t; int ok = (j < m);
        e0[t] = ok ? e[j] : 0; e1[t] = ok ? e[m + j] : 0; rr[t] = ok ? r[j] : 0;
    }
    float4 qa[B][EPW], kb[B][EPW];
    #pragma unroll
    for (int bb = 0; bb < B; ++bb)
        #pragma unroll
        for (int t = 0; t < EPW; ++t) {
            qa[bb][t] = ((const float4*)(q + ((size_t)bb * n + e0[t]) * D))[lane];
            kb[bb][t] = ((const float4*)(k + ((size_t)bb * n + e1[t]) * D))[lane];
        }
    #pragma unroll
    for (int bb = 0; bb < B; ++bb)
        #pragma unroll
        for (int t = 0; t < EPW; ++t) {
            float4 A = qa[bb][t], K4 = kb[bb][t];
            float p = A.x * K4.x + A.y * K4.y + A.z * K4.z + A.w * K4.w;
            p += __shfl_xor(p, 1); p += __shfl_xor(p, 2); p += __shfl_xor(p, 4);
            float ex = __expf(p * 0.0625f);
            if ((lane & 7) == 0 && (j0 + t) < m) {
                int h = lane >> 3;
                s[((size_t)bb * m + (j0 + t)) * NH + h] = ex;
                atomicAdd(&seg[((size_t)rr[t] * B + bb) * NH + h], ex);
            }
        }
}

// K2: one thread per (bb, edge). out = ex / (seg + eps), float4 in-place.
__global__ __launch_bounds__(256) void k_norm(
    float* __restrict__ s, const int* __restrict__ r,
    const float* __restrict__ seg, int m)
{
    int i = blockIdx.x * blockDim.x + threadIdx.x;
    int total = B * m;
    if (i >= total) return;
    int bb = (i >= m) ? 1 : 0;
    int j  = i - bb * m;
    const float4* sg = (const float4*)(seg + ((size_t)r[j] * B + bb) * NH);
    float4* sp = (float4*)(s + (size_t)i * NH);
    float4 d0 = sg[0], d1 = sg[1];
    float4 x0 = sp[0], x1 = sp[1];
    x0.x = __fdividef(x0.x, d0.x + 1e-16f);
    x0.y = __fdividef(x0.y, d0.y + 1e-16f);
    x0.z = __fdividef(x0.z, d0.z + 1e-16f);
    x0.w = __fdividef(x0.w, d0.w + 1e-16f);
    x1.x = __fdividef(x1.x, d1.x + 1e-16f);
    x1.y = __fdividef(x1.y, d1.y + 1e-16f);
    x1.z = __fdividef(x1.z, d1.z + 1e-16f);
    x1.w = __fdividef(x1.w, d1.w + 1e-16f);
    sp[0] = x0; sp[1] = x1;
}

extern "C" void kernel_launch(void* const* d_in, const int* in_sizes, int n_in,
                              void* d_out, int out_size, void* d_ws, size_t ws_size,
                              hipStream_t stream) {
    const float* q = (const float*)d_in[0];
    const float* k = (const float*)d_in[1];
    const int*   e = (const int*)d_in[2];
    const int*   r = (const int*)d_in[3];
    float* s = (float*)d_out;

    int n = in_sizes[0] / (B * D);          // 20000
    int m = in_sizes[3];                    // 320000

    // ws layout: seg | hist | cursor | qc | kc | perm
    size_t seg_bytes  = (size_t)n * B * NH * sizeof(float);          // 1.28 MB
    size_t sort_meta  = 2 * NBMAX * sizeof(int);                     // 4 KB
    size_t row_bytes  = (size_t)n * B * D * sizeof(unsigned short);  // 20.48 MB
    size_t perm_bytes = (size_t)m * sizeof(int4);                    // 5.12 MB

    float* seg    = (float*)d_ws;
    int*   hist   = (int*)((char*)d_ws + seg_bytes);
    int*   cursor = hist + NBMAX;
    ushort* qc = (ushort*)((char*)d_ws + seg_bytes + sort_meta);
    ushort* kc = (ushort*)((char*)d_ws + seg_bytes + sort_meta + row_bytes);
    int4*  perm = (int4*)((char*)d_ws + seg_bytes + sort_meta + 2 * row_bytes);

    bool use_bf16 = ws_size >= (seg_bytes + sort_meta + 2 * row_bytes);
    bool use_sort = use_bf16 &&
                    ws_size >= (seg_bytes + sort_meta + 2 * row_bytes + perm_bytes) &&
                    ((n + 63) >> 6) <= NBMAX;

    hipMemsetAsync(d_ws, 0, seg_bytes + sort_meta, stream);

    int nblocks = (B * m + 255) / 256;
    int nwaves  = (m + EPW - 1) / EPW;
    int sblocks = (nwaves + 3) / 4;

    if (use_bf16) {
        int cblocks = (n * B * 32 + 255) / 256;
        k_conv<<<cblocks, 256, 0, stream>>>(q, k, (uint4*)qc, (uint4*)kc, n);
        if (use_sort) {
            k_hist<<<256, 256, 0, stream>>>(e, hist, m);
            k_scan<<<1, NBMAX, 0, stream>>>(hist, cursor);
            k_scatter<<<256, 256, 0, stream>>>(e, r, cursor, perm, m);
            int do_swz = (sblocks % 8 == 0) ? 1 : 0;
            k_scores_perm<<<sblocks, 256, 0, stream>>>(qc, kc, perm, s, seg, m, do_swz);
        } else {
            k_scores_fused<<<sblocks, 256, 0, stream>>>(qc, kc, e, r, s, seg, m);
        }
    } else {
        k_scores_fused_f32<<<sblocks, 256, 0, stream>>>(q, k, e, r, s, seg, n, m);
    }
    k_norm<<<nblocks, 256, 0, stream>>>(s, r, seg, m);
}

// Round 5
// 306.124 us; speedup vs baseline: 1.0685x; 1.0685x over previous
//
#include <hip/hip_runtime.h>
#include <hip/hip_bf16.h>
#include <cmath>

#define D 256
#define NH 8
#define B 2
#define EPW 4      // edges per wave
#define NBMAX 512  // max buckets (bucket = node >> 6)
#define SBLK 1024  // edges per sort chunk

__device__ inline unsigned short f2bf(float f) {
    unsigned u = __float_as_uint(f);
    unsigned r = u + 0x7FFFu + ((u >> 16) & 1u);   // RNE
    return (unsigned short)(r >> 16);
}

// K0: fp32 [bb][node][d] -> packed bf16 [node][bb][d] (1KB per node covers
// both batches). One thread = 8 floats -> one 16B uint4 store.
__global__ __launch_bounds__(256) void k_conv(
    const float* __restrict__ q, const float* __restrict__ k,
    uint4* __restrict__ qc, uint4* __restrict__ kc, int n)
{
    int total = n * B * 32;
    for (int i = blockIdx.x * blockDim.x + threadIdx.x; i < total;
         i += gridDim.x * blockDim.x) {
        int c   = i & 31;
        int row = i >> 5;                 // bb*n + node
        int bb  = (row >= n) ? 1 : 0;
        int node = row - bb * n;
        const float4* qs = (const float4*)(q + ((size_t)row << 8)) + (c << 1);
        const float4* ks = (const float4*)(k + ((size_t)row << 8)) + (c << 1);
        float4 a0 = qs[0], a1 = qs[1];
        float4 b0 = ks[0], b1 = ks[1];
        uint4 pa, pb;
        pa.x = (unsigned)f2bf(a0.x) | ((unsigned)f2bf(a0.y) << 16);
        pa.y = (unsigned)f2bf(a0.z) | ((unsigned)f2bf(a0.w) << 16);
        pa.z = (unsigned)f2bf(a1.x) | ((unsigned)f2bf(a1.y) << 16);
        pa.w = (unsigned)f2bf(a1.z) | ((unsigned)f2bf(a1.w) << 16);
        pb.x = (unsigned)f2bf(b0.x) | ((unsigned)f2bf(b0.y) << 16);
        pb.y = (unsigned)f2bf(b0.z) | ((unsigned)f2bf(b0.w) << 16);
        pb.z = (unsigned)f2bf(b1.x) | ((unsigned)f2bf(b1.y) << 16);
        pb.w = (unsigned)f2bf(b1.z) | ((unsigned)f2bf(b1.w) << 16);
        size_t dst = ((size_t)node * B + bb) * 32 + c;
        qc[dst] = pa;
        kc[dst] = pb;
    }
}

// ---- Atomic-free counting sort (R4: round-3 k_scatter's 320K global
// atomics on 313 cursor words serialized ~1000-deep -> 131us. Classic
// block-decomposed scheme: per-chunk histogram, 2D offset scan, LDS-cursor
// scatter. ZERO global atomics.) ----

// A: chunk b's bucket histogram -> bh[b*nb + t] (block owns its row).
__global__ __launch_bounds__(256) void k_hist2(
    const int* __restrict__ e, int* __restrict__ bh, int m, int nb)
{
    __shared__ int lh[NBMAX];
    int b = blockIdx.x;
    int start = b * SBLK, end = min(m, start + SBLK);
    for (int t = threadIdx.x; t < nb; t += 256) lh[t] = 0;
    __syncthreads();
    for (int j = start + threadIdx.x; j < end; j += 256)
        atomicAdd(&lh[e[j] >> 6], 1);
    __syncthreads();
    for (int t = threadIdx.x; t < nb; t += 256)
        bh[(size_t)b * nb + t] = lh[t];
}

// B: in-place convert bh[b][t] into global write offsets:
// bh[b][t] = bucketbase[t] + sum_{b'<b} bh[b'][t]. Single block.
__global__ __launch_bounds__(NBMAX) void k_scan2(
    int* __restrict__ bh, int nch, int nb)
{
    __shared__ int tmp[NBMAX];
    int t = threadIdx.x;
    int tot = 0;
    if (t < nb)
        for (int b = 0; b < nch; ++b) tot += bh[(size_t)b * nb + t];
    tmp[t] = tot;
    __syncthreads();
    // exclusive scan over buckets (Hillis-Steele, uniform control flow)
    for (int off = 1; off < NBMAX; off <<= 1) {
        int v = (t >= off) ? tmp[t - off] : 0;
        __syncthreads();
        tmp[t] += v;
        __syncthreads();
    }
    int run = tmp[t] - tot;   // exclusive prefix = bucket base
    if (t < nb) {
        for (int b = 0; b < nch; ++b) {
            size_t idx = (size_t)b * nb + t;
            int c = bh[idx];
            bh[idx] = run;
            run += c;
        }
    }
}

// C: chunk b scatters its edges to reserved slots via LDS cursors.
// perm[pos] = {e0, e1, r, orig_j}. No stability needed (orig j carried).
__global__ __launch_bounds__(256) void k_scatter2(
    const int* __restrict__ e, const int* __restrict__ r,
    const int* __restrict__ bh, int4* __restrict__ perm, int m, int nb)
{
    __shared__ int cur[NBMAX];
    int b = blockIdx.x;
    int start = b * SBLK, end = min(m, start + SBLK);
    for (int t = threadIdx.x; t < nb; t += 256)
        cur[t] = bh[(size_t)b * nb + t];
    __syncthreads();
    for (int j = start + threadIdx.x; j < end; j += 256) {
        int e0 = e[j];
        int pos = atomicAdd(&cur[e0 >> 6], 1);   // LDS atomic, ~3 colliders
        perm[pos] = make_int4(e0, e[m + j], r[j], j);
    }
}

// K1: gather + scores + exp + segment atomicAdd over BUCKET-SORTED edges.
// q-side now has L2 locality: each XCD's chunk touches a ~2.6MB q-window.
__global__ __launch_bounds__(256) void k_scores_perm(
    const ushort* __restrict__ qc, const ushort* __restrict__ kc,
    const int4* __restrict__ perm,
    float* __restrict__ s, float* __restrict__ seg, int m, int do_swz)
{
    int bid = blockIdx.x;
    if (do_swz) {                       // XCD-chunked (bijective: grid%8==0)
        int nb8 = gridDim.x >> 3;
        bid = (bid & 7) * nb8 + (bid >> 3);
    }
    int wave = (bid << 2) + (threadIdx.x >> 6);
    int lane = threadIdx.x & 63;
    int j0 = wave * EPW;
    if (j0 >= m) return;

    int rr[EPW], jo[EPW];
    uint4 qa[EPW], kb[EPW];
    #pragma unroll
    for (int t = 0; t < EPW; ++t) {
        int j = j0 + t;
        int4 p = (j < m) ? perm[j] : make_int4(0, 0, 0, -1);
        rr[t] = p.z;
        jo[t] = p.w;   // original edge index (or -1 = inactive)
        qa[t] = ((const uint4*)(qc + (size_t)p.x * (B * D)))[lane];
        kb[t] = ((const uint4*)(kc + (size_t)p.y * (B * D)))[lane];
    }

    #pragma unroll
    for (int t = 0; t < EPW; ++t) {
        float p = 0.f;
        const unsigned* qw = (const unsigned*)&qa[t];
        const unsigned* kw = (const unsigned*)&kb[t];
        #pragma unroll
        for (int w = 0; w < 4; ++w) {
            float ql = __uint_as_float(qw[w] << 16);
            float qh = __uint_as_float(qw[w] & 0xFFFF0000u);
            float kl = __uint_as_float(kw[w] << 16);
            float kh = __uint_as_float(kw[w] & 0xFFFF0000u);
            p = fmaf(ql, kl, p);
            p = fmaf(qh, kh, p);
        }
        p += __shfl_xor(p, 1);
        p += __shfl_xor(p, 2);
        float ex = __expf(p * 0.0625f);     // /sqrt(256), no max shift
        if ((lane & 3) == 0 && jo[t] >= 0) {
            int bb = lane >> 5;
            int h  = (lane >> 2) & 7;
            s[((size_t)bb * m + jo[t]) * NH + h] = ex;
            atomicAdd(&seg[((size_t)rr[t] * B + bb) * NH + h], ex);
        }
    }
}

// K1-direct: original-order fallback (ws too small for sort buffers).
__global__ __launch_bounds__(256) void k_scores_fused(
    const ushort* __restrict__ qc, const ushort* __restrict__ kc,
    const int* __restrict__ e, const int* __restrict__ r,
    float* __restrict__ s, float* __restrict__ seg, int m)
{
    int wave = (int)((blockIdx.x * blockDim.x + threadIdx.x) >> 6);
    int lane = threadIdx.x & 63;
    int j0 = wave * EPW;
    if (j0 >= m) return;

    int e0[EPW], e1[EPW], rr[EPW];
    #pragma unroll
    for (int t = 0; t < EPW; ++t) {
        int j = j0 + t;
        int ok = (j < m);
        e0[t] = ok ? e[j]     : 0;
        e1[t] = ok ? e[m + j] : 0;
        rr[t] = ok ? r[j]     : 0;
    }
    uint4 qa[EPW], kb[EPW];
    #pragma unroll
    for (int t = 0; t < EPW; ++t) {
        qa[t] = ((const uint4*)(qc + (size_t)e0[t] * (B * D)))[lane];
        kb[t] = ((const uint4*)(kc + (size_t)e1[t] * (B * D)))[lane];
    }
    #pragma unroll
    for (int t = 0; t < EPW; ++t) {
        float p = 0.f;
        const unsigned* qw = (const unsigned*)&qa[t];
        const unsigned* kw = (const unsigned*)&kb[t];
        #pragma unroll
        for (int w = 0; w < 4; ++w) {
            float ql = __uint_as_float(qw[w] << 16);
            float qh = __uint_as_float(qw[w] & 0xFFFF0000u);
            float kl = __uint_as_float(kw[w] << 16);
            float kh = __uint_as_float(kw[w] & 0xFFFF0000u);
            p = fmaf(ql, kl, p);
            p = fmaf(qh, kh, p);
        }
        p += __shfl_xor(p, 1);
        p += __shfl_xor(p, 2);
        float ex = __expf(p * 0.0625f);
        if ((lane & 3) == 0 && (j0 + t) < m) {
            int bb = lane >> 5;
            int h  = (lane >> 2) & 7;
            s[((size_t)bb * m + (j0 + t)) * NH + h] = ex;
            atomicAdd(&seg[((size_t)rr[t] * B + bb) * NH + h], ex);
        }
    }
}

// fp32 fallback (ws too small for bf16 buffers): same fused structure.
__global__ __launch_bounds__(256) void k_scores_fused_f32(
    const float* __restrict__ q, const float* __restrict__ k,
    const int* __restrict__ e, const int* __restrict__ r,
    float* __restrict__ s, float* __restrict__ seg, int n, int m)
{
    int wave = (int)((blockIdx.x * blockDim.x + threadIdx.x) >> 6);
    int lane = threadIdx.x & 63;
    int j0 = wave * EPW;
    if (j0 >= m) return;
    int e0[EPW], e1[EPW], rr[EPW];
    #pragma unroll
    for (int t = 0; t < EPW; ++t) {
        int j = j0 + t; int ok = (j < m);
        e0[t] = ok ? e[j] : 0; e1[t] = ok ? e[m + j] : 0; rr[t] = ok ? r[j] : 0;
    }
    float4 qa[B][EPW], kb[B][EPW];
    #pragma unroll
    for (int bb = 0; bb < B; ++bb)
        #pragma unroll
        for (int t = 0; t < EPW; ++t) {
            qa[bb][t] = ((const float4*)(q + ((size_t)bb * n + e0[t]) * D))[lane];
            kb[bb][t] = ((const float4*)(k + ((size_t)bb * n + e1[t]) * D))[lane];
        }
    #pragma unroll
    for (int bb = 0; bb < B; ++bb)
        #pragma unroll
        for (int t = 0; t < EPW; ++t) {
            float4 A = qa[bb][t], K4 = kb[bb][t];
            float p = A.x * K4.x + A.y * K4.y + A.z * K4.z + A.w * K4.w;
            p += __shfl_xor(p, 1); p += __shfl_xor(p, 2); p += __shfl_xor(p, 4);
            float ex = __expf(p * 0.0625f);
            if ((lane & 7) == 0 && (j0 + t) < m) {
                int h = lane >> 3;
                s[((size_t)bb * m + (j0 + t)) * NH + h] = ex;
                atomicAdd(&seg[((size_t)rr[t] * B + bb) * NH + h], ex);
            }
        }
}

// K2: one thread per (bb, edge). out = ex / (seg + eps), float4 in-place.
__global__ __launch_bounds__(256) void k_norm(
    float* __restrict__ s, const int* __restrict__ r,
    const float* __restrict__ seg, int m)
{
    int i = blockIdx.x * blockDim.x + threadIdx.x;
    int total = B * m;
    if (i >= total) return;
    int bb = (i >= m) ? 1 : 0;
    int j  = i - bb * m;
    const float4* sg = (const float4*)(seg + ((size_t)r[j] * B + bb) * NH);
    float4* sp = (float4*)(s + (size_t)i * NH);
    float4 d0 = sg[0], d1 = sg[1];
    float4 x0 = sp[0], x1 = sp[1];
    x0.x = __fdividef(x0.x, d0.x + 1e-16f);
    x0.y = __fdividef(x0.y, d0.y + 1e-16f);
    x0.z = __fdividef(x0.z, d0.z + 1e-16f);
    x0.w = __fdividef(x0.w, d0.w + 1e-16f);
    x1.x = __fdividef(x1.x, d1.x + 1e-16f);
    x1.y = __fdividef(x1.y, d1.y + 1e-16f);
    x1.z = __fdividef(x1.z, d1.z + 1e-16f);
    x1.w = __fdividef(x1.w, d1.w + 1e-16f);
    sp[0] = x0; sp[1] = x1;
}

extern "C" void kernel_launch(void* const* d_in, const int* in_sizes, int n_in,
                              void* d_out, int out_size, void* d_ws, size_t ws_size,
                              hipStream_t stream) {
    const float* q = (const float*)d_in[0];
    const float* k = (const float*)d_in[1];
    const int*   e = (const int*)d_in[2];
    const int*   r = (const int*)d_in[3];
    float* s = (float*)d_out;

    int n = in_sizes[0] / (B * D);          // 20000
    int m = in_sizes[3];                    // 320000
    int nb  = (n + 63) >> 6;                // 313 buckets
    int nch = (m + SBLK - 1) / SBLK;        // 313 chunks

    // ws layout: seg | qc | kc | perm | blockhist
    size_t seg_bytes  = (size_t)n * B * NH * sizeof(float);          // 1.28 MB
    size_t row_bytes  = (size_t)n * B * D * sizeof(unsigned short);  // 20.48 MB
    size_t perm_bytes = (size_t)m * sizeof(int4);                    // 5.12 MB
    size_t bh_bytes   = (size_t)nch * nb * sizeof(int);              // ~0.4 MB

    float*  seg  = (float*)d_ws;
    ushort* qc   = (ushort*)((char*)d_ws + seg_bytes);
    ushort* kc   = (ushort*)((char*)d_ws + seg_bytes + row_bytes);
    int4*   perm = (int4*)((char*)d_ws + seg_bytes + 2 * row_bytes);
    int*    bh   = (int*)((char*)d_ws + seg_bytes + 2 * row_bytes + perm_bytes);

    bool use_bf16 = ws_size >= (seg_bytes + 2 * row_bytes);
    bool use_sort = use_bf16 && nb <= NBMAX &&
                    ws_size >= (seg_bytes + 2 * row_bytes + perm_bytes + bh_bytes);

    hipMemsetAsync(d_ws, 0, seg_bytes, stream);

    int nblocks = (B * m + 255) / 256;
    int nwaves  = (m + EPW - 1) / EPW;
    int sblocks = (nwaves + 3) / 4;

    if (use_bf16) {
        int cblocks = (n * B * 32 + 255) / 256;
        k_conv<<<cblocks, 256, 0, stream>>>(q, k, (uint4*)qc, (uint4*)kc, n);
        if (use_sort) {
            k_hist2<<<nch, 256, 0, stream>>>(e, bh, m, nb);
            k_scan2<<<1, NBMAX, 0, stream>>>(bh, nch, nb);
            k_scatter2<<<nch, 256, 0, stream>>>(e, r, bh, perm, m, nb);
            int do_swz = (sblocks % 8 == 0) ? 1 : 0;
            k_scores_perm<<<sblocks, 256, 0, stream>>>(qc, kc, perm, s, seg, m, do_swz);
        } else {
            k_scores_fused<<<sblocks, 256, 0, stream>>>(qc, kc, e, r, s, seg, m);
        }
    } else {
        k_scores_fused_f32<<<sblocks, 256, 0, stream>>>(q, k, e, r, s, seg, n, m);
    }
    k_norm<<<nblocks, 256, 0, stream>>>(s, r, seg, m);
}

// Round 6
// 208.213 us; speedup vs baseline: 1.5710x; 1.4702x over previous
//
#include <hip/hip_runtime.h>
#include <hip/hip_bf16.h>
#include <cmath>

#define D 256
#define NH 8
#define B 2
#define EPW 4      // edges per wave
#define NBMAX 512  // max buckets (bucket = node >> 6)
#define NCHMAX 512 // max sort chunks
#define SBLK 1024  // edges per sort chunk

__device__ inline unsigned short f2bf(float f) {
    unsigned u = __float_as_uint(f);
    unsigned r = u + 0x7FFFu + ((u >> 16) & 1u);   // RNE
    return (unsigned short)(r >> 16);
}

// K0: fp32 [bb][node][d] -> packed bf16 [node][bb][d] (1KB per node covers
// both batches). One thread = 8 floats -> one 16B uint4 store.
__global__ __launch_bounds__(256) void k_conv(
    const float* __restrict__ q, const float* __restrict__ k,
    uint4* __restrict__ qc, uint4* __restrict__ kc, int n)
{
    int total = n * B * 32;
    for (int i = blockIdx.x * blockDim.x + threadIdx.x; i < total;
         i += gridDim.x * blockDim.x) {
        int c   = i & 31;
        int row = i >> 5;                 // bb*n + node
        int bb  = (row >= n) ? 1 : 0;
        int node = row - bb * n;
        const float4* qs = (const float4*)(q + ((size_t)row << 8)) + (c << 1);
        const float4* ks = (const float4*)(k + ((size_t)row << 8)) + (c << 1);
        float4 a0 = qs[0], a1 = qs[1];
        float4 b0 = ks[0], b1 = ks[1];
        uint4 pa, pb;
        pa.x = (unsigned)f2bf(a0.x) | ((unsigned)f2bf(a0.y) << 16);
        pa.y = (unsigned)f2bf(a0.z) | ((unsigned)f2bf(a0.w) << 16);
        pa.z = (unsigned)f2bf(a1.x) | ((unsigned)f2bf(a1.y) << 16);
        pa.w = (unsigned)f2bf(a1.z) | ((unsigned)f2bf(a1.w) << 16);
        pb.x = (unsigned)f2bf(b0.x) | ((unsigned)f2bf(b0.y) << 16);
        pb.y = (unsigned)f2bf(b0.z) | ((unsigned)f2bf(b0.w) << 16);
        pb.z = (unsigned)f2bf(b1.x) | ((unsigned)f2bf(b1.y) << 16);
        pb.w = (unsigned)f2bf(b1.z) | ((unsigned)f2bf(b1.w) << 16);
        size_t dst = ((size_t)node * B + bb) * 32 + c;
        qc[dst] = pa;
        kc[dst] = pb;
    }
}

// ---- Atomic-free counting sort.
// R4: global-atomic scatter was 131us (320K atomics on 313 words).
// R5: single-block k_scan2 was 107us (2x serial 313-iter loops at L2
// latency from ONE CU). This round: the 2D scan is decomposed into
// nb PARALLEL per-column scans + one tiny 313-elem base scan. ----

// A: chunk b's bucket histogram -> bh[b*nb + t] (block owns its row).
__global__ __launch_bounds__(256) void k_hist2(
    const int* __restrict__ e, int* __restrict__ bh, int m, int nb)
{
    __shared__ int lh[NBMAX];
    int b = blockIdx.x;
    int start = b * SBLK, end = min(m, start + SBLK);
    for (int t = threadIdx.x; t < nb; t += 256) lh[t] = 0;
    __syncthreads();
    for (int j = start + threadIdx.x; j < end; j += 256)
        atomicAdd(&lh[e[j] >> 6], 1);
    __syncthreads();
    for (int t = threadIdx.x; t < nb; t += 256)
        bh[(size_t)b * nb + t] = lh[t];
}

// B1: per-bucket column scan. Block t: exclusive-scan bh[.][t] over chunks
// (each thread holds one chunk's count -> LDS Hillis-Steele), write back
// prefixes, emit column total. 313 blocks run concurrently (vs R5's one).
__global__ __launch_bounds__(NCHMAX) void k_colscan(
    int* __restrict__ bh, int* __restrict__ tot, int nch, int nb)
{
    __shared__ int tmp[NCHMAX];
    int t = blockIdx.x;           // bucket
    int b = threadIdx.x;          // chunk
    int v = (b < nch) ? bh[(size_t)b * nb + t] : 0;
    tmp[b] = v;
    __syncthreads();
    for (int off = 1; off < NCHMAX; off <<= 1) {   // uniform control flow
        int u = (b >= off) ? tmp[b - off] : 0;
        __syncthreads();
        tmp[b] += u;
        __syncthreads();
    }
    if (b < nch) bh[(size_t)b * nb + t] = tmp[b] - v;  // excl. prefix in column
    if (b == NCHMAX - 1) tot[t] = tmp[b];              // column total
}

// B2: single-block exclusive scan over the nb bucket totals -> base[t].
// Only nb(=313) elements -- microseconds.
__global__ __launch_bounds__(NBMAX) void k_basescan(
    const int* __restrict__ tot, int* __restrict__ base, int nb)
{
    __shared__ int tmp[NBMAX];
    int t = threadIdx.x;
    int v = (t < nb) ? tot[t] : 0;
    tmp[t] = v;
    __syncthreads();
    for (int off = 1; off < NBMAX; off <<= 1) {
        int u = (t >= off) ? tmp[t - off] : 0;
        __syncthreads();
        tmp[t] += u;
        __syncthreads();
    }
    if (t < nb) base[t] = tmp[t] - v;
}

// C: chunk b scatters its edges via LDS cursors seeded with
// base[t] + column-prefix. perm[pos] = {e0, e1, r, orig_j}.
__global__ __launch_bounds__(256) void k_scatter2(
    const int* __restrict__ e, const int* __restrict__ r,
    const int* __restrict__ bh, const int* __restrict__ base,
    int4* __restrict__ perm, int m, int nb)
{
    __shared__ int cur[NBMAX];
    int b = blockIdx.x;
    int start = b * SBLK, end = min(m, start + SBLK);
    for (int t = threadIdx.x; t < nb; t += 256)
        cur[t] = bh[(size_t)b * nb + t] + base[t];
    __syncthreads();
    for (int j = start + threadIdx.x; j < end; j += 256) {
        int e0 = e[j];
        int pos = atomicAdd(&cur[e0 >> 6], 1);   // LDS atomic, ~3 colliders
        perm[pos] = make_int4(e0, e[m + j], r[j], j);
    }
}

// K1: gather + scores + exp + segment atomicAdd over BUCKET-SORTED edges.
// q-side gains L2 locality: each XCD chunk touches a ~2.6MB q-window.
__global__ __launch_bounds__(256) void k_scores_perm(
    const ushort* __restrict__ qc, const ushort* __restrict__ kc,
    const int4* __restrict__ perm,
    float* __restrict__ s, float* __restrict__ seg, int m, int do_swz)
{
    int bid = blockIdx.x;
    if (do_swz) {                       // XCD-chunked (bijective: grid%8==0)
        int nb8 = gridDim.x >> 3;
        bid = (bid & 7) * nb8 + (bid >> 3);
    }
    int wave = (bid << 2) + (threadIdx.x >> 6);
    int lane = threadIdx.x & 63;
    int j0 = wave * EPW;
    if (j0 >= m) return;

    int rr[EPW], jo[EPW];
    uint4 qa[EPW], kb[EPW];
    #pragma unroll
    for (int t = 0; t < EPW; ++t) {
        int j = j0 + t;
        int4 p = (j < m) ? perm[j] : make_int4(0, 0, 0, -1);
        rr[t] = p.z;
        jo[t] = p.w;   // original edge index (or -1 = inactive)
        qa[t] = ((const uint4*)(qc + (size_t)p.x * (B * D)))[lane];
        kb[t] = ((const uint4*)(kc + (size_t)p.y * (B * D)))[lane];
    }

    #pragma unroll
    for (int t = 0; t < EPW; ++t) {
        float p = 0.f;
        const unsigned* qw = (const unsigned*)&qa[t];
        const unsigned* kw = (const unsigned*)&kb[t];
        #pragma unroll
        for (int w = 0; w < 4; ++w) {
            float ql = __uint_as_float(qw[w] << 16);
            float qh = __uint_as_float(qw[w] & 0xFFFF0000u);
            float kl = __uint_as_float(kw[w] << 16);
            float kh = __uint_as_float(kw[w] & 0xFFFF0000u);
            p = fmaf(ql, kl, p);
            p = fmaf(qh, kh, p);
        }
        p += __shfl_xor(p, 1);
        p += __shfl_xor(p, 2);
        float ex = __expf(p * 0.0625f);     // /sqrt(256), no max shift
        if ((lane & 3) == 0 && jo[t] >= 0) {
            int bb = lane >> 5;
            int h  = (lane >> 2) & 7;
            s[((size_t)bb * m + jo[t]) * NH + h] = ex;
            atomicAdd(&seg[((size_t)rr[t] * B + bb) * NH + h], ex);
        }
    }
}

// K1-direct: original-order fallback (ws too small for sort buffers).
__global__ __launch_bounds__(256) void k_scores_fused(
    const ushort* __restrict__ qc, const ushort* __restrict__ kc,
    const int* __restrict__ e, const int* __restrict__ r,
    float* __restrict__ s, float* __restrict__ seg, int m)
{
    int wave = (int)((blockIdx.x * blockDim.x + threadIdx.x) >> 6);
    int lane = threadIdx.x & 63;
    int j0 = wave * EPW;
    if (j0 >= m) return;

    int e0[EPW], e1[EPW], rr[EPW];
    #pragma unroll
    for (int t = 0; t < EPW; ++t) {
        int j = j0 + t;
        int ok = (j < m);
        e0[t] = ok ? e[j]     : 0;
        e1[t] = ok ? e[m + j] : 0;
        rr[t] = ok ? r[j]     : 0;
    }
    uint4 qa[EPW], kb[EPW];
    #pragma unroll
    for (int t = 0; t < EPW; ++t) {
        qa[t] = ((const uint4*)(qc + (size_t)e0[t] * (B * D)))[lane];
        kb[t] = ((const uint4*)(kc + (size_t)e1[t] * (B * D)))[lane];
    }
    #pragma unroll
    for (int t = 0; t < EPW; ++t) {
        float p = 0.f;
        const unsigned* qw = (const unsigned*)&qa[t];
        const unsigned* kw = (const unsigned*)&kb[t];
        #pragma unroll
        for (int w = 0; w < 4; ++w) {
            float ql = __uint_as_float(qw[w] << 16);
            float qh = __uint_as_float(qw[w] & 0xFFFF0000u);
            float kl = __uint_as_float(kw[w] << 16);
            float kh = __uint_as_float(kw[w] & 0xFFFF0000u);
            p = fmaf(ql, kl, p);
            p = fmaf(qh, kh, p);
        }
        p += __shfl_xor(p, 1);
        p += __shfl_xor(p, 2);
        float ex = __expf(p * 0.0625f);
        if ((lane & 3) == 0 && (j0 + t) < m) {
            int bb = lane >> 5;
            int h  = (lane >> 2) & 7;
            s[((size_t)bb * m + (j0 + t)) * NH + h] = ex;
            atomicAdd(&seg[((size_t)rr[t] * B + bb) * NH + h], ex);
        }
    }
}

// fp32 fallback (ws too small for bf16 buffers): same fused structure.
__global__ __launch_bounds__(256) void k_scores_fused_f32(
    const float* __restrict__ q, const float* __restrict__ k,
    const int* __restrict__ e, const int* __restrict__ r,
    float* __restrict__ s, float* __restrict__ seg, int n, int m)
{
    int wave = (int)((blockIdx.x * blockDim.x + threadIdx.x) >> 6);
    int lane = threadIdx.x & 63;
    int j0 = wave * EPW;
    if (j0 >= m) return;
    int e0[EPW], e1[EPW], rr[EPW];
    #pragma unroll
    for (int t = 0; t < EPW; ++t) {
        int j = j0 + t; int ok = (j < m);
        e0[t] = ok ? e[j] : 0; e1[t] = ok ? e[m + j] : 0; rr[t] = ok ? r[j] : 0;
    }
    float4 qa[B][EPW], kb[B][EPW];
    #pragma unroll
    for (int bb = 0; bb < B; ++bb)
        #pragma unroll
        for (int t = 0; t < EPW; ++t) {
            qa[bb][t] = ((const float4*)(q + ((size_t)bb * n + e0[t]) * D))[lane];
            kb[bb][t] = ((const float4*)(k + ((size_t)bb * n + e1[t]) * D))[lane];
        }
    #pragma unroll
    for (int bb = 0; bb < B; ++bb)
        #pragma unroll
        for (int t = 0; t < EPW; ++t) {
            float4 A = qa[bb][t], K4 = kb[bb][t];
            float p = A.x * K4.x + A.y * K4.y + A.z * K4.z + A.w * K4.w;
            p += __shfl_xor(p, 1); p += __shfl_xor(p, 2); p += __shfl_xor(p, 4);
            float ex = __expf(p * 0.0625f);
            if ((lane & 7) == 0 && (j0 + t) < m) {
                int h = lane >> 3;
                s[((size_t)bb * m + (j0 + t)) * NH + h] = ex;
                atomicAdd(&seg[((size_t)rr[t] * B + bb) * NH + h], ex);
            }
        }
}

// K2: one thread per (bb, edge). out = ex / (seg + eps), float4 in-place.
__global__ __launch_bounds__(256) void k_norm(
    float* __restrict__ s, const int* __restrict__ r,
    const float* __restrict__ seg, int m)
{
    int i = blockIdx.x * blockDim.x + threadIdx.x;
    int total = B * m;
    if (i >= total) return;
    int bb = (i >= m) ? 1 : 0;
    int j  = i - bb * m;
    const float4* sg = (const float4*)(seg + ((size_t)r[j] * B + bb) * NH);
    float4* sp = (float4*)(s + (size_t)i * NH);
    float4 d0 = sg[0], d1 = sg[1];
    float4 x0 = sp[0], x1 = sp[1];
    x0.x = __fdividef(x0.x, d0.x + 1e-16f);
    x0.y = __fdividef(x0.y, d0.y + 1e-16f);
    x0.z = __fdividef(x0.z, d0.z + 1e-16f);
    x0.w = __fdividef(x0.w, d0.w + 1e-16f);
    x1.x = __fdividef(x1.x, d1.x + 1e-16f);
    x1.y = __fdividef(x1.y, d1.y + 1e-16f);
    x1.z = __fdividef(x1.z, d1.z + 1e-16f);
    x1.w = __fdividef(x1.w, d1.w + 1e-16f);
    sp[0] = x0; sp[1] = x1;
}

extern "C" void kernel_launch(void* const* d_in, const int* in_sizes, int n_in,
                              void* d_out, int out_size, void* d_ws, size_t ws_size,
                              hipStream_t stream) {
    const float* q = (const float*)d_in[0];
    const float* k = (const float*)d_in[1];
    const int*   e = (const int*)d_in[2];
    const int*   r = (const int*)d_in[3];
    float* s = (float*)d_out;

    int n = in_sizes[0] / (B * D);          // 20000
    int m = in_sizes[3];                    // 320000
    int nb  = (n + 63) >> 6;                // 313 buckets
    int nch = (m + SBLK - 1) / SBLK;        // 313 chunks

    // ws layout: seg | qc | kc | perm | bh | tot | base
    size_t seg_bytes  = (size_t)n * B * NH * sizeof(float);          // 1.28 MB
    size_t row_bytes  = (size_t)n * B * D * sizeof(unsigned short);  // 20.48 MB
    size_t perm_bytes = (size_t)m * sizeof(int4);                    // 5.12 MB
    size_t bh_bytes   = (size_t)nch * nb * sizeof(int);              // ~0.4 MB
    size_t tb_bytes   = 2 * NBMAX * sizeof(int);                     // 4 KB

    float*  seg  = (float*)d_ws;
    ushort* qc   = (ushort*)((char*)d_ws + seg_bytes);
    ushort* kc   = (ushort*)((char*)d_ws + seg_bytes + row_bytes);
    int4*   perm = (int4*)((char*)d_ws + seg_bytes + 2 * row_bytes);
    int*    bh   = (int*)((char*)d_ws + seg_bytes + 2 * row_bytes + perm_bytes);
    int*    tot  = (int*)((char*)bh + bh_bytes);
    int*    base = tot + NBMAX;

    bool use_bf16 = ws_size >= (seg_bytes + 2 * row_bytes);
    bool use_sort = use_bf16 && nb <= NBMAX && nch <= NCHMAX &&
                    ws_size >= (seg_bytes + 2 * row_bytes + perm_bytes +
                                bh_bytes + tb_bytes);

    hipMemsetAsync(d_ws, 0, seg_bytes, stream);

    int nblocks = (B * m + 255) / 256;
    int nwaves  = (m + EPW - 1) / EPW;
    int sblocks = (nwaves + 3) / 4;

    if (use_bf16) {
        int cblocks = (n * B * 32 + 255) / 256;
        k_conv<<<cblocks, 256, 0, stream>>>(q, k, (uint4*)qc, (uint4*)kc, n);
        if (use_sort) {
            k_hist2<<<nch, 256, 0, stream>>>(e, bh, m, nb);
            k_colscan<<<nb, NCHMAX, 0, stream>>>(bh, tot, nch, nb);
            k_basescan<<<1, NBMAX, 0, stream>>>(tot, base, nb);
            k_scatter2<<<nch, 256, 0, stream>>>(e, r, bh, base, perm, m, nb);
            int do_swz = (sblocks % 8 == 0) ? 1 : 0;
            k_scores_perm<<<sblocks, 256, 0, stream>>>(qc, kc, perm, s, seg, m, do_swz);
        } else {
            k_scores_fused<<<sblocks, 256, 0, stream>>>(qc, kc, e, r, s, seg, m);
        }
    } else {
        k_scores_fused_f32<<<sblocks, 256, 0, stream>>>(q, k, e, r, s, seg, n, m);
    }
    k_norm<<<nblocks, 256, 0, stream>>>(s, r, seg, m);
}

// Round 7
// 206.614 us; speedup vs baseline: 1.5831x; 1.0077x over previous
//
#include <hip/hip_runtime.h>
#include <hip/hip_bf16.h>
#include <cmath>

#define D 256
#define NH 8
#define B 2
#define EPW 4      // edges per wave
#define NBMAX 512  // max buckets (bucket = node >> 6)
#define NCHMAX 512 // max sort chunks
#define SBLK 1024  // edges per sort chunk

#if defined(__has_builtin)
#  if __has_builtin(__builtin_amdgcn_fdot2_f32_bf16)
#    define USE_BF16_DOT 1
#  else
#    define USE_BF16_DOT 0
#  endif
#else
#  define USE_BF16_DOT 0
#endif

#if USE_BF16_DOT
typedef __bf16 bf16x2 __attribute__((ext_vector_type(2)));
#endif

__device__ inline unsigned short f2bf(float f) {
    unsigned u = __float_as_uint(f);
    unsigned r = u + 0x7FFFu + ((u >> 16) & 1u);   // RNE
    return (unsigned short)(r >> 16);
}

// 16-elem bf16 dot (one uint4 pair): v_dot2_f32_bf16 when available,
// else shift/and unpack + fmaf.
__device__ inline float dot16(const uint4& a, const uint4& b) {
    float p = 0.f;
#if USE_BF16_DOT
    const bf16x2* av = (const bf16x2*)&a;
    const bf16x2* bv = (const bf16x2*)&b;
    #pragma unroll
    for (int w = 0; w < 4; ++w)
        p = __builtin_amdgcn_fdot2_f32_bf16(av[w], bv[w], p, false);
#else
    const unsigned* aw = (const unsigned*)&a;
    const unsigned* bw = (const unsigned*)&b;
    #pragma unroll
    for (int w = 0; w < 4; ++w) {
        float al = __uint_as_float(aw[w] << 16);
        float ah = __uint_as_float(aw[w] & 0xFFFF0000u);
        float bl = __uint_as_float(bw[w] << 16);
        float bh = __uint_as_float(bw[w] & 0xFFFF0000u);
        p = fmaf(al, bl, p);
        p = fmaf(ah, bh, p);
    }
#endif
    return p;
}

// K0: fp32 [bb][node][d] -> packed bf16 [node][bb][d] (1KB per node covers
// both batches). Also zeroes seg (replaces a memset dispatch).
__global__ __launch_bounds__(256) void k_conv(
    const float* __restrict__ q, const float* __restrict__ k,
    uint4* __restrict__ qc, uint4* __restrict__ kc,
    float* __restrict__ seg, int segN, int n)
{
    int tid    = blockIdx.x * blockDim.x + threadIdx.x;
    int stride = gridDim.x * blockDim.x;
    for (int i = tid; i < segN; i += stride) seg[i] = 0.f;
    int total = n * B * 32;
    for (int i = tid; i < total; i += stride) {
        int c   = i & 31;
        int row = i >> 5;                 // bb*n + node
        int bb  = (row >= n) ? 1 : 0;
        int node = row - bb * n;
        const float4* qs = (const float4*)(q + ((size_t)row << 8)) + (c << 1);
        const float4* ks = (const float4*)(k + ((size_t)row << 8)) + (c << 1);
        float4 a0 = qs[0], a1 = qs[1];
        float4 b0 = ks[0], b1 = ks[1];
        uint4 pa, pb;
        pa.x = (unsigned)f2bf(a0.x) | ((unsigned)f2bf(a0.y) << 16);
        pa.y = (unsigned)f2bf(a0.z) | ((unsigned)f2bf(a0.w) << 16);
        pa.z = (unsigned)f2bf(a1.x) | ((unsigned)f2bf(a1.y) << 16);
        pa.w = (unsigned)f2bf(a1.z) | ((unsigned)f2bf(a1.w) << 16);
        pb.x = (unsigned)f2bf(b0.x) | ((unsigned)f2bf(b0.y) << 16);
        pb.y = (unsigned)f2bf(b0.z) | ((unsigned)f2bf(b0.w) << 16);
        pb.z = (unsigned)f2bf(b1.x) | ((unsigned)f2bf(b1.y) << 16);
        pb.w = (unsigned)f2bf(b1.z) | ((unsigned)f2bf(b1.w) << 16);
        size_t dst = ((size_t)node * B + bb) * 32 + c;
        qc[dst] = pa;
        kc[dst] = pb;
    }
}

// ---- Atomic-free counting sort (R6-verbatim: hist + parallel column scan
// + tiny base scan + LDS-cursor scatter; total ~17us). ----

__global__ __launch_bounds__(256) void k_hist2(
    const int* __restrict__ e, int* __restrict__ bh, int m, int nb)
{
    __shared__ int lh[NBMAX];
    int b = blockIdx.x;
    int start = b * SBLK, end = min(m, start + SBLK);
    for (int t = threadIdx.x; t < nb; t += 256) lh[t] = 0;
    __syncthreads();
    for (int j = start + threadIdx.x; j < end; j += 256)
        atomicAdd(&lh[e[j] >> 6], 1);
    __syncthreads();
    for (int t = threadIdx.x; t < nb; t += 256)
        bh[(size_t)b * nb + t] = lh[t];
}

__global__ __launch_bounds__(NCHMAX) void k_colscan(
    int* __restrict__ bh, int* __restrict__ tot, int nch, int nb)
{
    __shared__ int tmp[NCHMAX];
    int t = blockIdx.x;           // bucket
    int b = threadIdx.x;          // chunk
    int v = (b < nch) ? bh[(size_t)b * nb + t] : 0;
    tmp[b] = v;
    __syncthreads();
    for (int off = 1; off < NCHMAX; off <<= 1) {   // uniform control flow
        int u = (b >= off) ? tmp[b - off] : 0;
        __syncthreads();
        tmp[b] += u;
        __syncthreads();
    }
    if (b < nch) bh[(size_t)b * nb + t] = tmp[b] - v;  // excl. prefix in column
    if (b == NCHMAX - 1) tot[t] = tmp[b];              // column total
}

__global__ __launch_bounds__(NBMAX) void k_basescan(
    const int* __restrict__ tot, int* __restrict__ base, int nb)
{
    __shared__ int tmp[NBMAX];
    int t = threadIdx.x;
    int v = (t < nb) ? tot[t] : 0;
    tmp[t] = v;
    __syncthreads();
    for (int off = 1; off < NBMAX; off <<= 1) {
        int u = (t >= off) ? tmp[t - off] : 0;
        __syncthreads();
        tmp[t] += u;
        __syncthreads();
    }
    if (t < nb) base[t] = tmp[t] - v;
}

__global__ __launch_bounds__(256) void k_scatter2(
    const int* __restrict__ e, const int* __restrict__ r,
    const int* __restrict__ bh, const int* __restrict__ base,
    int4* __restrict__ perm, int m, int nb)
{
    __shared__ int cur[NBMAX];
    int b = blockIdx.x;
    int start = b * SBLK, end = min(m, start + SBLK);
    for (int t = threadIdx.x; t < nb; t += 256)
        cur[t] = bh[(size_t)b * nb + t] + base[t];
    __syncthreads();
    for (int j = start + threadIdx.x; j < end; j += 256) {
        int e0 = e[j];
        int pos = atomicAdd(&cur[e0 >> 6], 1);   // LDS atomic, ~3 colliders
        perm[pos] = make_int4(e0, e[m + j], r[j], j);
    }
}

// K1: gather + scores + exp + segment atomicAdd over BUCKET-SORTED edges.
// R7: re-add sched_barrier(0) after the gather-issue loop (VGPR_Count was
// 28 -> compiler sank the 8 gathers to uses, ~2 in flight, latency-bound
// at 40% HBM / 47% VALU / 71% occ). EPW stays 4 (clean A/B vs R2's
// confounded EPW8+barrier). Plus v_dot2_f32_bf16 for the dot product.
__global__ __launch_bounds__(256) void k_scores_perm(
    const ushort* __restrict__ qc, const ushort* __restrict__ kc,
    const int4* __restrict__ perm,
    float* __restrict__ s, float* __restrict__ seg, int m, int do_swz)
{
    int bid = blockIdx.x;
    if (do_swz) {                       // XCD-chunked (bijective: grid%8==0)
        int nb8 = gridDim.x >> 3;
        bid = (bid & 7) * nb8 + (bid >> 3);
    }
    int wave = (bid << 2) + (threadIdx.x >> 6);
    int lane = threadIdx.x & 63;
    int j0 = wave * EPW;
    if (j0 >= m) return;

    int rr[EPW], jo[EPW];
    uint4 qa[EPW], kb[EPW];
    #pragma unroll
    for (int t = 0; t < EPW; ++t) {
        int j = j0 + t;
        int4 p = (j < m) ? perm[j] : make_int4(0, 0, 0, -1);
        rr[t] = p.z;
        jo[t] = p.w;   // original edge index (or -1 = inactive)
        qa[t] = ((const uint4*)(qc + (size_t)p.x * (B * D)))[lane];
        kb[t] = ((const uint4*)(kc + (size_t)p.y * (B * D)))[lane];
    }
    __builtin_amdgcn_sched_barrier(0);   // keep all 8 gathers in flight

    #pragma unroll
    for (int t = 0; t < EPW; ++t) {
        float p = dot16(qa[t], kb[t]);
        p += __shfl_xor(p, 1);
        p += __shfl_xor(p, 2);
        float ex = __expf(p * 0.0625f);     // /sqrt(256), no max shift
        if ((lane & 3) == 0 && jo[t] >= 0) {
            int bb = lane >> 5;
            int h  = (lane >> 2) & 7;
            s[((size_t)bb * m + jo[t]) * NH + h] = ex;
            atomicAdd(&seg[((size_t)rr[t] * B + bb) * NH + h], ex);
        }
    }
}

// K1-direct: original-order fallback (ws too small for sort buffers).
__global__ __launch_bounds__(256) void k_scores_fused(
    const ushort* __restrict__ qc, const ushort* __restrict__ kc,
    const int* __restrict__ e, const int* __restrict__ r,
    float* __restrict__ s, float* __restrict__ seg, int m)
{
    int wave = (int)((blockIdx.x * blockDim.x + threadIdx.x) >> 6);
    int lane = threadIdx.x & 63;
    int j0 = wave * EPW;
    if (j0 >= m) return;

    int e0[EPW], e1[EPW], rr[EPW];
    #pragma unroll
    for (int t = 0; t < EPW; ++t) {
        int j = j0 + t;
        int ok = (j < m);
        e0[t] = ok ? e[j]     : 0;
        e1[t] = ok ? e[m + j] : 0;
        rr[t] = ok ? r[j]     : 0;
    }
    uint4 qa[EPW], kb[EPW];
    #pragma unroll
    for (int t = 0; t < EPW; ++t) {
        qa[t] = ((const uint4*)(qc + (size_t)e0[t] * (B * D)))[lane];
        kb[t] = ((const uint4*)(kc + (size_t)e1[t] * (B * D)))[lane];
    }
    __builtin_amdgcn_sched_barrier(0);
    #pragma unroll
    for (int t = 0; t < EPW; ++t) {
        float p = dot16(qa[t], kb[t]);
        p += __shfl_xor(p, 1);
        p += __shfl_xor(p, 2);
        float ex = __expf(p * 0.0625f);
        if ((lane & 3) == 0 && (j0 + t) < m) {
            int bb = lane >> 5;
            int h  = (lane >> 2) & 7;
            s[((size_t)bb * m + (j0 + t)) * NH + h] = ex;
            atomicAdd(&seg[((size_t)rr[t] * B + bb) * NH + h], ex);
        }
    }
}

// fp32 fallback (ws too small for bf16 buffers): same fused structure.
__global__ __launch_bounds__(256) void k_scores_fused_f32(
    const float* __restrict__ q, const float* __restrict__ k,
    const int* __restrict__ e, const int* __restrict__ r,
    float* __restrict__ s, float* __restrict__ seg, int n, int m)
{
    int wave = (int)((blockIdx.x * blockDim.x + threadIdx.x) >> 6);
    int lane = threadIdx.x & 63;
    int j0 = wave * EPW;
    if (j0 >= m) return;
    int e0[EPW], e1[EPW], rr[EPW];
    #pragma unroll
    for (int t = 0; t < EPW; ++t) {
        int j = j0 + t; int ok = (j < m);
        e0[t] = ok ? e[j] : 0; e1[t] = ok ? e[m + j] : 0; rr[t] = ok ? r[j] : 0;
    }
    float4 qa[B][EPW], kb[B][EPW];
    #pragma unroll
    for (int bb = 0; bb < B; ++bb)
        #pragma unroll
        for (int t = 0; t < EPW; ++t) {
            qa[bb][t] = ((const float4*)(q + ((size_t)bb * n + e0[t]) * D))[lane];
            kb[bb][t] = ((const float4*)(k + ((size_t)bb * n + e1[t]) * D))[lane];
        }
    #pragma unroll
    for (int bb = 0; bb < B; ++bb)
        #pragma unroll
        for (int t = 0; t < EPW; ++t) {
            float4 A = qa[bb][t], K4 = kb[bb][t];
            float p = A.x * K4.x + A.y * K4.y + A.z * K4.z + A.w * K4.w;
            p += __shfl_xor(p, 1); p += __shfl_xor(p, 2); p += __shfl_xor(p, 4);
            float ex = __expf(p * 0.0625f);
            if ((lane & 7) == 0 && (j0 + t) < m) {
                int h = lane >> 3;
                s[((size_t)bb * m + (j0 + t)) * NH + h] = ex;
                atomicAdd(&seg[((size_t)rr[t] * B + bb) * NH + h], ex);
            }
        }
}

// K2: one thread per (bb, edge). out = ex / (seg + eps), float4 in-place.
__global__ __launch_bounds__(256) void k_norm(
    float* __restrict__ s, const int* __restrict__ r,
    const float* __restrict__ seg, int m)
{
    int i = blockIdx.x * blockDim.x + threadIdx.x;
    int total = B * m;
    if (i >= total) return;
    int bb = (i >= m) ? 1 : 0;
    int j  = i - bb * m;
    const float4* sg = (const float4*)(seg + ((size_t)r[j] * B + bb) * NH);
    float4* sp = (float4*)(s + (size_t)i * NH);
    float4 d0 = sg[0], d1 = sg[1];
    float4 x0 = sp[0], x1 = sp[1];
    x0.x = __fdividef(x0.x, d0.x + 1e-16f);
    x0.y = __fdividef(x0.y, d0.y + 1e-16f);
    x0.z = __fdividef(x0.z, d0.z + 1e-16f);
    x0.w = __fdividef(x0.w, d0.w + 1e-16f);
    x1.x = __fdividef(x1.x, d1.x + 1e-16f);
    x1.y = __fdividef(x1.y, d1.y + 1e-16f);
    x1.z = __fdividef(x1.z, d1.z + 1e-16f);
    x1.w = __fdividef(x1.w, d1.w + 1e-16f);
    sp[0] = x0; sp[1] = x1;
}

extern "C" void kernel_launch(void* const* d_in, const int* in_sizes, int n_in,
                              void* d_out, int out_size, void* d_ws, size_t ws_size,
                              hipStream_t stream) {
    const float* q = (const float*)d_in[0];
    const float* k = (const float*)d_in[1];
    const int*   e = (const int*)d_in[2];
    const int*   r = (const int*)d_in[3];
    float* s = (float*)d_out;

    int n = in_sizes[0] / (B * D);          // 20000
    int m = in_sizes[3];                    // 320000
    int nb  = (n + 63) >> 6;                // 313 buckets
    int nch = (m + SBLK - 1) / SBLK;        // 313 chunks
    int segN = n * B * NH;                  // 320000 floats

    // ws layout: seg | qc | kc | perm | bh | tot | base
    size_t seg_bytes  = (size_t)segN * sizeof(float);                // 1.28 MB
    size_t row_bytes  = (size_t)n * B * D * sizeof(unsigned short);  // 20.48 MB
    size_t perm_bytes = (size_t)m * sizeof(int4);                    // 5.12 MB
    size_t bh_bytes   = (size_t)nch * nb * sizeof(int);              // ~0.4 MB
    size_t tb_bytes   = 2 * NBMAX * sizeof(int);                     // 4 KB

    float*  seg  = (float*)d_ws;
    ushort* qc   = (ushort*)((char*)d_ws + seg_bytes);
    ushort* kc   = (ushort*)((char*)d_ws + seg_bytes + row_bytes);
    int4*   perm = (int4*)((char*)d_ws + seg_bytes + 2 * row_bytes);
    int*    bh   = (int*)((char*)d_ws + seg_bytes + 2 * row_bytes + perm_bytes);
    int*    tot  = (int*)((char*)bh + bh_bytes);
    int*    base = tot + NBMAX;

    bool use_bf16 = ws_size >= (seg_bytes + 2 * row_bytes);
    bool use_sort = use_bf16 && nb <= NBMAX && nch <= NCHMAX &&
                    ws_size >= (seg_bytes + 2 * row_bytes + perm_bytes +
                                bh_bytes + tb_bytes);

    int nblocks = (B * m + 255) / 256;
    int nwaves  = (m + EPW - 1) / EPW;
    int sblocks = (nwaves + 3) / 4;

    if (use_bf16) {
        int cblocks = (n * B * 32 + 255) / 256;
        k_conv<<<cblocks, 256, 0, stream>>>(q, k, (uint4*)qc, (uint4*)kc,
                                            seg, segN, n);
        if (use_sort) {
            k_hist2<<<nch, 256, 0, stream>>>(e, bh, m, nb);
            k_colscan<<<nb, NCHMAX, 0, stream>>>(bh, tot, nch, nb);
            k_basescan<<<1, NBMAX, 0, stream>>>(tot, base, nb);
            k_scatter2<<<nch, 256, 0, stream>>>(e, r, bh, base, perm, m, nb);
            int do_swz = (sblocks % 8 == 0) ? 1 : 0;
            k_scores_perm<<<sblocks, 256, 0, stream>>>(qc, kc, perm, s, seg, m, do_swz);
        } else {
            k_scores_fused<<<sblocks, 256, 0, stream>>>(qc, kc, e, r, s, seg, m);
        }
    } else {
        hipMemsetAsync(d_ws, 0, seg_bytes, stream);
        k_scores_fused_f32<<<sblocks, 256, 0, stream>>>(q, k, e, r, s, seg, n, m);
    }
    k_norm<<<nblocks, 256, 0, stream>>>(s, r, seg, m);
}